// Round 6
// baseline (319.446 us; speedup 1.0000x reference)
//
#include <hip/hip_runtime.h>

// Problem constants
#define QN    2048
#define SS    8
#define DD    2048
#define SP    100
#define NCLS  20
#define MROWS (QN*SS)       // 16384 GEMM M
#define NROWS (SP*SS)       // 800   logical N
#define NPAD  896           // padded N (7*128)
#define KK    DD

typedef __bf16 bf16x8 __attribute__((ext_vector_type(8)));
typedef float  f32x16 __attribute__((ext_vector_type(16)));

__device__ __forceinline__ unsigned short f2bf(float f) {
    unsigned int u = __float_as_uint(f);
    u += 0x7fffu + ((u >> 16) & 1u);   // round-to-nearest-even
    return (unsigned short)(u >> 16);
}

// ---------------- Kernel 1: fp32 -> bf16 conversion + row L2 norms ----------------
// One WAVE per row (no barriers, no LDS). 4 rows per 256-thread block.
__global__ void cvt_kernel(const float* __restrict__ tf, const float* __restrict__ sf,
                           unsigned short* __restrict__ Abf, unsigned short* __restrict__ Bbf,
                           float* __restrict__ nA, float* __restrict__ nB)
{
    const int wv   = threadIdx.x >> 6;
    const int lane = threadIdx.x & 63;
    const int row  = blockIdx.x * 4 + wv;       // 0 .. 17279

    const float* src = nullptr;
    unsigned short* dst;
    float* nrm; int r;
    if (row < MROWS) { src = tf + (size_t)row * DD; dst = Abf + (size_t)row * DD; nrm = nA; r = row; }
    else {
        r = row - MROWS;
        dst = Bbf + (size_t)r * DD; nrm = nB;
        if (r < NROWS) src = sf + (size_t)r * DD;   // rows [800,896) stay zero
    }

    float s = 0.f;
#pragma unroll
    for (int j = 0; j < 8; j++) {
        ushort4 pk = make_ushort4(0, 0, 0, 0);
        if (src) {
            float4 v = *(const float4*)(src + j * 256 + lane * 4);
            s += v.x*v.x + v.y*v.y + v.z*v.z + v.w*v.w;
            pk = make_ushort4(f2bf(v.x), f2bf(v.y), f2bf(v.z), f2bf(v.w));
        }
        *(ushort4*)(dst + j * 256 + lane * 4) = pk;
    }
#pragma unroll
    for (int o = 32; o; o >>= 1) s += __shfl_down(s, o);
    if (lane == 0) nrm[r] = sqrtf(s);
}

// ---------------- softmin helpers ----------------
__device__ __forceinline__ float softmin2(float a, float b) {
    float mn = fminf(a, b), mx = fmaxf(a, b);
    return mn - 0.1f * __logf(1.0f + __expf((mn - mx) * 10.0f));
}
__device__ __forceinline__ float softmin3(float a, float b, float c) {
    float mn = fminf(fminf(a, b), c);
    float sum = __expf((mn - a) * 10.0f) + __expf((mn - b) * 10.0f) + __expf((mn - c) * 10.0f);
    return mn - 0.1f * __logf(sum);
}

__device__ __forceinline__ void gld16(const void* g, void* l) {
    __builtin_amdgcn_global_load_lds(
        (const __attribute__((address_space(1))) unsigned int*)g,
        (__attribute__((address_space(3))) unsigned int*)l, 16, 0, 0);
}

// bf16 cell (a,b) of lane's 8x8 tile held in 8 uint4 registers -> fp32
__device__ __forceinline__ float cellf(const uint4* raw, int a, int b) {
    const unsigned* p = (const unsigned*)raw;
    unsigned wv = p[a * 4 + (b >> 1)];
    return __uint_as_float((b & 1) ? (wv & 0xffff0000u) : (wv << 16));
}

#define EBS (32 * 72)   // shorts per wave epilogue buffer (32 rows x 64 cols, pad to 72)

// ---------------- Kernel 2: 128x128 bf16 GEMM via 32x32x16 MFMA, fused OTAM DP ------
__global__ __launch_bounds__(256, 4) void gemm_kernel(
    const unsigned short* __restrict__ A,   // [MROWS][K] bf16 bits
    const unsigned short* __restrict__ B,   // [NPAD][K]  bf16 bits
    const float* __restrict__ nA, const float* __restrict__ nB,
    float* __restrict__ cum)                // [QN][SP]
{
    // staging 16 KB (A 8 KB + B 8 KB), aliased with 4 x 4608 B epilogue buffers
    __shared__ __align__(16) unsigned short smem[4 * EBS];   // 18432 B
    unsigned short* Als = smem;             // 128 rows x 32 k, row-major
    unsigned short* Bls = smem + 4096;

    const int mt  = blockIdx.x;      // 0..127
    const int nt  = blockIdx.y;      // 0..6
    const int tid = threadIdx.x;
    const int lane = tid & 63;
    const int w    = tid >> 6;
    const int wm   = (w & 1) * 64, wn = (w >> 1) * 64;
    const int r32  = lane & 31;          // row/col within a 32-block
    const int hi   = lane >> 5;          // k-half-of-8 selector

    f32x16 acc[2][2] = {};

    // staging: 512 16B chunks per operand, 2 per thread; chunk c -> row c>>2, ksub (c&3)*8
    const int c0 = tid, c1 = tid + 256;
    const unsigned short* Ab0 = A + (size_t)(mt * 128 + (c0 >> 2)) * KK + (c0 & 3) * 8;
    const unsigned short* Ab1 = A + (size_t)(mt * 128 + (c1 >> 2)) * KK + (c1 & 3) * 8;
    const unsigned short* Bb0 = B + (size_t)(nt * 128 + (c0 >> 2)) * KK + (c0 & 3) * 8;
    const unsigned short* Bb1 = B + (size_t)(nt * 128 + (c1 >> 2)) * KK + (c1 & 3) * 8;

    for (int kk = 0; kk < KK; kk += 32) {
        __syncthreads();
        gld16(Ab0 + kk, (char*)Als + c0 * 16);
        gld16(Ab1 + kk, (char*)Als + c1 * 16);
        gld16(Bb0 + kk, (char*)Bls + c0 * 16);
        gld16(Bb1 + kk, (char*)Bls + c1 * 16);
        __syncthreads();
        // 32x32x16 fragments: A[m=lane&31][k=hi*8+j]; 2 k-halves of 16 within BK=32
#pragma unroll
        for (int kh = 0; kh < 2; kh++) {
            bf16x8 af[2], bfr[2];
#pragma unroll
            for (int mi = 0; mi < 2; mi++)
                af[mi]  = *(const bf16x8*)(Als + (wm + mi * 32 + r32) * 32 + kh * 16 + hi * 8);
#pragma unroll
            for (int ni = 0; ni < 2; ni++)
                bfr[ni] = *(const bf16x8*)(Bls + (wn + ni * 32 + r32) * 32 + kh * 16 + hi * 8);
#pragma unroll
            for (int mi = 0; mi < 2; mi++)
#pragma unroll
                for (int ni = 0; ni < 2; ni++)
                    acc[mi][ni] = __builtin_amdgcn_mfma_f32_32x32x16_bf16(af[mi], bfr[ni], acc[mi][ni], 0, 0, 0);
        }
    }

    // ---------------- fused epilogue: dist(bf16) -> LDS -> register DP -> cum -------
    __syncthreads();   // all waves done reading staging LDS (epilogue aliases it)

    unsigned short* eb = smem + w * EBS;
    const int mbase = mt * 128 + wm;
    const int nbase = nt * 128 + wn;
    const int pr  = lane & 31;
    const int qv2 = pr >> 3, sv = pr & 7;
    const int dir = lane >> 5;

    float ny0 = nB[nbase + r32];
    float ny1 = nB[nbase + 32 + r32];

#pragma unroll
    for (int p = 0; p < 2; p++) {        // phase p handles wave-tile rows [p*32, p*32+32)
        if (p) __syncthreads();          // phase-0 DP reads done before phase-1 writes
        const int mi = p;                // 32x32 row-block == phase
#pragma unroll
        for (int reg = 0; reg < 16; reg++) {
            const int lrow = (reg & 3) + 8 * (reg >> 2) + 4 * hi;   // 0..31
            const float nx = nA[mbase + mi * 32 + lrow];
            float d0 = 1.0f - acc[mi][0][reg] * __builtin_amdgcn_rcpf(nx * ny0 + 0.01f);
            float d1 = 1.0f - acc[mi][1][reg] * __builtin_amdgcn_rcpf(nx * ny1 + 0.01f);
            eb[lrow * 72 + r32]      = f2bf(d0);
            eb[lrow * 72 + 32 + r32] = f2bf(d1);
        }
        __syncthreads();   // writes visible before DP reads

        // DP: 32 pairs (4 qv x 8 sv) x 2 dirs = 64 lanes; tile in regs, free transpose
        uint4 raw[8];
        const unsigned short* tb = eb + (qv2 * 8) * 72 + sv * 8;
#pragma unroll
        for (int l = 0; l < 8; l++) raw[l] = *(const uint4*)(tb + l * 72);

        float prev[10], cur[10];
        prev[0] = 0.f;
#pragma unroll
        for (int m = 1; m <= 8; m++) {
            float v0 = cellf(raw, 0, m - 1), v1 = cellf(raw, m - 1, 0);
            prev[m] = prev[m - 1] + (dir ? v1 : v0);
        }
        prev[9] = prev[8];
#pragma unroll
        for (int l = 1; l < 8; l++) {
            float d[8];
#pragma unroll
            for (int j = 0; j < 8; j++) {
                float v0 = cellf(raw, l, j), v1 = cellf(raw, j, l);
                d[j] = dir ? v1 : v0;
            }
            cur[1] = d[0] + softmin3(prev[0], prev[1], 0.0f);
#pragma unroll
            for (int m = 2; m <= 8; m++)
                cur[m] = d[m - 1] + softmin2(prev[m - 1], cur[m - 1]);
            cur[9] = softmin3(prev[8], prev[9], cur[8]);   // pad column: d=0
#pragma unroll
            for (int m = 1; m < 10; m++) prev[m] = cur[m];
        }
        float res = prev[9];
        res += __shfl_down(res, 32);    // combine the two directions
        if (dir == 0) {
            const int qg = mt * 16 + (wm >> 3) + p * 4 + qv2;
            const int sg = nt * 16 + (wn >> 3) + sv;
            if (sg < SP) cum[(size_t)qg * SP + sg] = res;
        }
    }
}

// ---------------- Kernel 3: per-class mean -> logits ----------------
__global__ void cls_kernel(const float* __restrict__ cum, const int* __restrict__ labels,
                           float* __restrict__ out)
{
    int idx = blockIdx.x * 256 + threadIdx.x;   // 40960 exactly
    int q = idx / NCLS, c = idx % NCLS;
    float s = 0.f; int n = 0;
    const float* row = cum + (size_t)q * SP;
    for (int sp = 0; sp < SP; sp++) {
        if (labels[sp] == c) { s += row[sp]; n++; }
    }
    out[idx] = -s / (float)n;
}

// ---------------- launch ----------------
extern "C" void kernel_launch(void* const* d_in, const int* in_sizes, int n_in,
                              void* d_out, int out_size, void* d_ws, size_t ws_size,
                              hipStream_t stream)
{
    const float* tf     = (const float*)d_in[0];   // [2048,8,2048] f32
    const float* sf     = (const float*)d_in[1];   // [100,8,2048]  f32
    const int*   labels = (const int*)d_in[2];     // [100] i32
    float* out = (float*)d_out;                    // [1,2048,20] f32

    char* ws = (char*)d_ws;
    const size_t szA    = (size_t)MROWS * KK * 2;      // 67108864
    const size_t szB    = (size_t)NPAD  * KK * 2;      // 3670016
    const size_t szNA   = (size_t)MROWS * 4;           // 65536
    const size_t szNB   = (size_t)NPAD  * 4;           // 3584
    unsigned short* Abf = (unsigned short*)ws;
    unsigned short* Bbf = (unsigned short*)(ws + szA);
    float* nA   = (float*)(ws + szA + szB);
    float* nB   = (float*)(ws + szA + szB + szNA);
    float* cum  = (float*)(ws + szA + szB + szNA + szNB);   // [2048][100]

    cvt_kernel<<<(MROWS + NPAD) / 4, 256, 0, stream>>>(tf, sf, Abf, Bbf, nA, nB);
    gemm_kernel<<<dim3(MROWS / 128, NPAD / 128), 256, 0, stream>>>(Abf, Bbf, nA, nB, cum);
    cls_kernel<<<160, 256, 0, stream>>>(cum, labels, out);
}

// Round 7
// 315.240 us; speedup vs baseline: 1.0133x; 1.0133x over previous
//
#include <hip/hip_runtime.h>

// Problem constants
#define QN    2048
#define SS    8
#define DD    2048
#define SP    100
#define NCLS  20
#define MROWS (QN*SS)       // 16384 GEMM M
#define NROWS (SP*SS)       // 800   logical N
#define NPAD  832           // 6*128 + 64 (full tiles + tail tile)
#define KK    DD

typedef __bf16 bf16x8 __attribute__((ext_vector_type(8)));
typedef float  f32x4  __attribute__((ext_vector_type(4)));

__device__ __forceinline__ unsigned short f2bf(float f) {
    unsigned int u = __float_as_uint(f);
    u += 0x7fffu + ((u >> 16) & 1u);   // round-to-nearest-even
    return (unsigned short)(u >> 16);
}

// ---------------- Kernel 1: fp32 -> bf16 conversion + row L2 norms ----------------
// One WAVE per row (no barriers, no LDS). 4 rows per 256-thread block.
__global__ void cvt_kernel(const float* __restrict__ tf, const float* __restrict__ sf,
                           unsigned short* __restrict__ Abf, unsigned short* __restrict__ Bbf,
                           float* __restrict__ nA, float* __restrict__ nB)
{
    const int wv   = threadIdx.x >> 6;
    const int lane = threadIdx.x & 63;
    const int row  = blockIdx.x * 4 + wv;       // 0 .. 17215

    const float* src = nullptr;
    unsigned short* dst;
    float* nrm; int r;
    if (row < MROWS) { src = tf + (size_t)row * DD; dst = Abf + (size_t)row * DD; nrm = nA; r = row; }
    else {
        r = row - MROWS;
        dst = Bbf + (size_t)r * DD; nrm = nB;
        if (r < NROWS) src = sf + (size_t)r * DD;   // rows [800,832) stay zero
    }

    float s = 0.f;
#pragma unroll
    for (int j = 0; j < 8; j++) {
        ushort4 pk = make_ushort4(0, 0, 0, 0);
        if (src) {
            float4 v = *(const float4*)(src + j * 256 + lane * 4);
            s += v.x*v.x + v.y*v.y + v.z*v.z + v.w*v.w;
            pk = make_ushort4(f2bf(v.x), f2bf(v.y), f2bf(v.z), f2bf(v.w));
        }
        *(ushort4*)(dst + j * 256 + lane * 4) = pk;
    }
#pragma unroll
    for (int o = 32; o; o >>= 1) s += __shfl_down(s, o);
    if (lane == 0) nrm[r] = sqrtf(s);
}

// ---------------- softmin helpers ----------------
__device__ __forceinline__ float softmin2(float a, float b) {
    float mn = fminf(a, b), mx = fmaxf(a, b);
    return mn - 0.1f * __logf(1.0f + __expf((mn - mx) * 10.0f));
}
__device__ __forceinline__ float softmin3(float a, float b, float c) {
    float mn = fminf(fminf(a, b), c);
    float sum = __expf((mn - a) * 10.0f) + __expf((mn - b) * 10.0f) + __expf((mn - c) * 10.0f);
    return mn - 0.1f * __logf(sum);
}

__device__ __forceinline__ void gld16(const void* g, void* l) {
    __builtin_amdgcn_global_load_lds(
        (const __attribute__((address_space(1))) unsigned int*)g,
        (__attribute__((address_space(3))) unsigned int*)l, 16, 0, 0);
}

// bf16 cell (a,b) of lane's 8x8 tile held in 8 uint4 registers -> fp32
__device__ __forceinline__ float cellf(const uint4* raw, int a, int b) {
    const unsigned* p = (const unsigned*)raw;
    unsigned wv = p[a * 4 + (b >> 1)];
    return __uint_as_float((b & 1) ? (wv & 0xffff0000u) : (wv << 16));
}

// OTAM DP over the lane's 8x8 tile (both triangular variants via dir), returns final cost
__device__ __forceinline__ float otam_dp(const uint4* raw, int dir) {
    float prev[10], cur[10];
    prev[0] = 0.f;
#pragma unroll
    for (int m = 1; m <= 8; m++) {
        float v0 = cellf(raw, 0, m - 1), v1 = cellf(raw, m - 1, 0);
        prev[m] = prev[m - 1] + (dir ? v1 : v0);
    }
    prev[9] = prev[8];
#pragma unroll
    for (int l = 1; l < 8; l++) {
        float d[8];
#pragma unroll
        for (int j = 0; j < 8; j++) {
            float v0 = cellf(raw, l, j), v1 = cellf(raw, j, l);
            d[j] = dir ? v1 : v0;
        }
        cur[1] = d[0] + softmin3(prev[0], prev[1], 0.0f);
#pragma unroll
        for (int m = 2; m <= 8; m++)
            cur[m] = d[m - 1] + softmin2(prev[m - 1], cur[m - 1]);
        cur[9] = softmin3(prev[8], prev[9], cur[8]);   // pad column: d=0
#pragma unroll
        for (int m = 1; m < 10; m++) prev[m] = cur[m];
    }
    return prev[9];
}

#define EBS (32 * 72)   // shorts per wave epilogue buffer (full kernel): 32 rows x 64 cols pad 72

// ---------------- Kernel 2a: 128x128 bf16 MFMA GEMM (R5 config) + fused DP + class mean ----
__global__ __launch_bounds__(256, 4) void gemm_full(
    const unsigned short* __restrict__ A,   // [MROWS][K] bf16 bits
    const unsigned short* __restrict__ B,   // [NPAD][K]  bf16 bits
    const float* __restrict__ nA, const float* __restrict__ nB,
    const int* __restrict__ labels,
    float* __restrict__ out)                // [QN][NCLS], zero-initialized
{
    __shared__ __align__(16) unsigned short smem[4 * EBS];   // 18432 B (staging 16 KB aliased)
    unsigned short* Als = smem;             // 128*32
    unsigned short* Bls = smem + 4096;

    const int mt  = blockIdx.x;      // 0..127
    const int nt  = blockIdx.y;      // 0..5
    const int tid = threadIdx.x;
    const int lane = tid & 63;
    const int w    = tid >> 6;
    const int wm   = (w & 1) * 64, wn = (w >> 1) * 64;
    const int col  = lane & 15, kg = lane >> 4;

    f32x4 acc[4][4] = {};

    const int c0 = tid, c1 = tid + 256;
    const unsigned short* Ab0 = A + (size_t)(mt * 128 + (c0 >> 2)) * KK + (c0 & 3) * 8;
    const unsigned short* Ab1 = A + (size_t)(mt * 128 + (c1 >> 2)) * KK + (c1 & 3) * 8;
    const unsigned short* Bb0 = B + (size_t)(nt * 128 + (c0 >> 2)) * KK + (c0 & 3) * 8;
    const unsigned short* Bb1 = B + (size_t)(nt * 128 + (c1 >> 2)) * KK + (c1 & 3) * 8;

    for (int kk = 0; kk < KK; kk += 32) {
        __syncthreads();
        gld16(Ab0 + kk, (char*)Als + c0 * 16);
        gld16(Ab1 + kk, (char*)Als + c1 * 16);
        gld16(Bb0 + kk, (char*)Bls + c0 * 16);
        gld16(Bb1 + kk, (char*)Bls + c1 * 16);
        __syncthreads();
        bf16x8 af[4], bfr[4];
#pragma unroll
        for (int i = 0; i < 4; i++) af[i]  = *(const bf16x8*)(Als + (wm + i * 16 + col) * 32 + kg * 8);
#pragma unroll
        for (int i = 0; i < 4; i++) bfr[i] = *(const bf16x8*)(Bls + (wn + i * 16 + col) * 32 + kg * 8);
#pragma unroll
        for (int mi = 0; mi < 4; mi++)
#pragma unroll
            for (int ni = 0; ni < 4; ni++)
                acc[mi][ni] = __builtin_amdgcn_mfma_f32_16x16x32_bf16(af[mi], bfr[ni], acc[mi][ni], 0, 0, 0);
    }

    // fused epilogue: dist(bf16) -> LDS -> register DP -> atomic class mean
    __syncthreads();   // staging reads done (epilogue aliases)

    unsigned short* eb = smem + w * EBS;
    const int mbase = mt * 128 + wm;
    const int nbase = nt * 128 + wn;
    const int pr  = lane & 31;
    const int qv2 = pr >> 3, sv = pr & 7;
    const int dir = lane >> 5;

#pragma unroll
    for (int p = 0; p < 2; p++) {
        if (p) __syncthreads();
#pragma unroll
        for (int mi2 = 0; mi2 < 2; mi2++) {
            const int mi = p * 2 + mi2;
            float nx[4];
#pragma unroll
            for (int r = 0; r < 4; r++) nx[r] = nA[mbase + mi * 16 + kg * 4 + r];
#pragma unroll
            for (int ni = 0; ni < 4; ni++) {
                const float ny = nB[nbase + ni * 16 + col];
#pragma unroll
                for (int r = 0; r < 4; r++) {
                    float d = 1.0f - acc[mi][ni][r] * __builtin_amdgcn_rcpf(nx[r] * ny + 0.01f);
                    eb[(mi2 * 16 + kg * 4 + r) * 72 + ni * 16 + col] = f2bf(d);
                }
            }
        }
        __syncthreads();

        uint4 raw[8];
        const unsigned short* tb = eb + (qv2 * 8) * 72 + sv * 8;
#pragma unroll
        for (int l = 0; l < 8; l++) raw[l] = *(const uint4*)(tb + l * 72);

        float res = otam_dp(raw, dir);
        res += __shfl_down(res, 32);
        if (dir == 0) {
            const int qg = mt * 16 + (wm >> 3) + p * 4 + qv2;
            const int sg = nt * 16 + (wn >> 3) + sv;
            if (sg < SP) atomicAdd(out + (size_t)qg * NCLS + labels[sg], -res * 0.2f);
        }
    }
}

// ---------------- Kernel 2b: 128x64 tail tile (N rows 768..831) ----------------
#define EBH (64 * 40)   // shorts per wave epilogue buffer: 64 rows x 32 cols pad 40

__global__ __launch_bounds__(256, 4) void gemm_half(
    const unsigned short* __restrict__ A,
    const unsigned short* __restrict__ B,
    const float* __restrict__ nA, const float* __restrict__ nB,
    const int* __restrict__ labels,
    float* __restrict__ out)
{
    __shared__ __align__(16) unsigned short smem[4 * EBH];   // 20480 B (staging 12 KB aliased)
    unsigned short* Als = smem;             // 128*32
    unsigned short* Bls = smem + 4096;      // 64*32

    const int mt  = blockIdx.x;      // 0..127
    const int tid = threadIdx.x;
    const int lane = tid & 63;
    const int w    = tid >> 6;
    const int wm   = (w & 1) * 64, wn = (w >> 1) * 32;
    const int col  = lane & 15, kg = lane >> 4;

    f32x4 acc[4][2] = {};

    const int c0 = tid, c1 = tid + 256;
    const unsigned short* Ab0 = A + (size_t)(mt * 128 + (c0 >> 2)) * KK + (c0 & 3) * 8;
    const unsigned short* Ab1 = A + (size_t)(mt * 128 + (c1 >> 2)) * KK + (c1 & 3) * 8;
    const unsigned short* Bb0 = B + (size_t)(768 + (c0 >> 2)) * KK + (c0 & 3) * 8;  // 256 chunks

    for (int kk = 0; kk < KK; kk += 32) {
        __syncthreads();
        gld16(Ab0 + kk, (char*)Als + c0 * 16);
        gld16(Ab1 + kk, (char*)Als + c1 * 16);
        gld16(Bb0 + kk, (char*)Bls + c0 * 16);
        __syncthreads();
        bf16x8 af[4], bfr[2];
#pragma unroll
        for (int i = 0; i < 4; i++) af[i]  = *(const bf16x8*)(Als + (wm + i * 16 + col) * 32 + kg * 8);
#pragma unroll
        for (int i = 0; i < 2; i++) bfr[i] = *(const bf16x8*)(Bls + (wn + i * 16 + col) * 32 + kg * 8);
#pragma unroll
        for (int mi = 0; mi < 4; mi++)
#pragma unroll
            for (int ni = 0; ni < 2; ni++)
                acc[mi][ni] = __builtin_amdgcn_mfma_f32_16x16x32_bf16(af[mi], bfr[ni], acc[mi][ni], 0, 0, 0);
    }

    __syncthreads();   // staging reads done (epilogue aliases)

    unsigned short* eb = smem + w * EBH;
    const int mbase = mt * 128 + wm;
    const int nbase = 768 + wn;

    // write the wave's full 64x32 dist sub-tile as bf16
#pragma unroll
    for (int mi = 0; mi < 4; mi++) {
        float nx[4];
#pragma unroll
        for (int r = 0; r < 4; r++) nx[r] = nA[mbase + mi * 16 + kg * 4 + r];
#pragma unroll
        for (int ni = 0; ni < 2; ni++) {
            const float ny = nB[nbase + ni * 16 + col];
#pragma unroll
            for (int r = 0; r < 4; r++) {
                float d = 1.0f - acc[mi][ni][r] * __builtin_amdgcn_rcpf(nx[r] * ny + 0.01f);
                eb[(mi * 16 + kg * 4 + r) * 40 + ni * 16 + col] = f2bf(d);
            }
        }
    }
    __syncthreads();

    // DP: 8 qv x 4 sv = 32 pairs x 2 dirs = 64 lanes
    const int pr  = lane & 31;
    const int qv  = pr >> 2, sv = pr & 3;
    const int dir = lane >> 5;
    uint4 raw[8];
    const unsigned short* tb = eb + (qv * 8) * 40 + sv * 8;
#pragma unroll
    for (int l = 0; l < 8; l++) raw[l] = *(const uint4*)(tb + l * 40);

    float res = otam_dp(raw, dir);
    res += __shfl_down(res, 32);
    if (dir == 0) {
        const int qg = mt * 16 + (wm >> 3) + qv;
        const int sg = 96 + (wn >> 3) + sv;
        if (sg < SP) atomicAdd(out + (size_t)qg * NCLS + labels[sg], -res * 0.2f);
    }
}

// ---------------- launch ----------------
extern "C" void kernel_launch(void* const* d_in, const int* in_sizes, int n_in,
                              void* d_out, int out_size, void* d_ws, size_t ws_size,
                              hipStream_t stream)
{
    const float* tf     = (const float*)d_in[0];   // [2048,8,2048] f32
    const float* sf     = (const float*)d_in[1];   // [100,8,2048]  f32
    const int*   labels = (const int*)d_in[2];     // [100] i32
    float* out = (float*)d_out;                    // [1,2048,20] f32

    char* ws = (char*)d_ws;
    const size_t szA    = (size_t)MROWS * KK * 2;      // 67108864
    const size_t szB    = (size_t)NPAD  * KK * 2;      // 3407872
    const size_t szNA   = (size_t)MROWS * 4;           // 65536
    unsigned short* Abf = (unsigned short*)ws;
    unsigned short* Bbf = (unsigned short*)(ws + szA);
    float* nA   = (float*)(ws + szA + szB);
    float* nB   = (float*)(ws + szA + szB + szNA);

    hipMemsetAsync(out, 0, (size_t)QN * NCLS * sizeof(float), stream);
    cvt_kernel<<<(MROWS + NPAD) / 4, 256, 0, stream>>>(tf, sf, Abf, Bbf, nA, nB);
    gemm_full<<<dim3(MROWS / 128, 6), 256, 0, stream>>>(Abf, Bbf, nA, nB, labels, out);
    gemm_half<<<MROWS / 128, 256, 0, stream>>>(Abf, Bbf, nA, nB, labels, out);
}

// Round 8
// 278.715 us; speedup vs baseline: 1.1461x; 1.1310x over previous
//
#include <hip/hip_runtime.h>

// Problem constants
#define QN    2048
#define SS    8
#define DD    2048
#define SP    100
#define NCLS  20
#define MROWS (QN*SS)       // 16384 GEMM M
#define NROWS (SP*SS)       // 800   logical N
#define NPAD  800           // no padding: 6 full 128-tiles + one 32-wide tail
#define KK    DD

typedef __bf16 bf16x8 __attribute__((ext_vector_type(8)));
typedef float  f32x4  __attribute__((ext_vector_type(4)));

__device__ __forceinline__ unsigned short f2bf(float f) {
    unsigned int u = __float_as_uint(f);
    u += 0x7fffu + ((u >> 16) & 1u);   // round-to-nearest-even
    return (unsigned short)(u >> 16);
}

// ---------------- Kernel 1: fp32 -> bf16 + row L2 norms + out zeroing ----------------
// One WAVE per row (no barriers, no LDS). 4 rows per 256-thread block.
__global__ void cvt_kernel(const float* __restrict__ tf, const float* __restrict__ sf,
                           unsigned short* __restrict__ Abf, unsigned short* __restrict__ Bbf,
                           float* __restrict__ nA, float* __restrict__ nB,
                           float* __restrict__ out)
{
    // zero the logits output (gemm accumulates atomically): 160*256 = 40960 elems
    if (blockIdx.x < 160) out[blockIdx.x * 256 + threadIdx.x] = 0.f;

    const int wv   = threadIdx.x >> 6;
    const int lane = threadIdx.x & 63;
    const int row  = blockIdx.x * 4 + wv;       // 0 .. 17183

    const float* src;
    unsigned short* dst;
    float* nrm; int r;
    if (row < MROWS) { src = tf + (size_t)row * DD; dst = Abf + (size_t)row * DD; nrm = nA; r = row; }
    else {
        r = row - MROWS;                        // 0..799, all real
        src = sf + (size_t)r * DD; dst = Bbf + (size_t)r * DD; nrm = nB;
    }

    float s = 0.f;
#pragma unroll
    for (int j = 0; j < 8; j++) {
        float4 v = *(const float4*)(src + j * 256 + lane * 4);
        s += v.x*v.x + v.y*v.y + v.z*v.z + v.w*v.w;
        ushort4 pk = make_ushort4(f2bf(v.x), f2bf(v.y), f2bf(v.z), f2bf(v.w));
        *(ushort4*)(dst + j * 256 + lane * 4) = pk;
    }
#pragma unroll
    for (int o = 32; o; o >>= 1) s += __shfl_down(s, o);
    if (lane == 0) nrm[r] = sqrtf(s);
}

// ---------------- softmin helpers ----------------
__device__ __forceinline__ float softmin2(float a, float b) {
    float mn = fminf(a, b), mx = fmaxf(a, b);
    return mn - 0.1f * __logf(1.0f + __expf((mn - mx) * 10.0f));
}
__device__ __forceinline__ float softmin3(float a, float b, float c) {
    float mn = fminf(fminf(a, b), c);
    float sum = __expf((mn - a) * 10.0f) + __expf((mn - b) * 10.0f) + __expf((mn - c) * 10.0f);
    return mn - 0.1f * __logf(sum);
}

__device__ __forceinline__ void gld16(const void* g, void* l) {
    __builtin_amdgcn_global_load_lds(
        (const __attribute__((address_space(1))) unsigned int*)g,
        (__attribute__((address_space(3))) unsigned int*)l, 16, 0, 0);
}

// bf16 cell (a,b) of lane's 8x8 tile held in 8 uint4 registers -> fp32
__device__ __forceinline__ float cellf(const uint4* raw, int a, int b) {
    const unsigned* p = (const unsigned*)raw;
    unsigned wv = p[a * 4 + (b >> 1)];
    return __uint_as_float((b & 1) ? (wv & 0xffff0000u) : (wv << 16));
}

// OTAM DP over the lane's 8x8 tile (dir selects transpose), returns final cost
__device__ __forceinline__ float otam_dp(const uint4* raw, int dir) {
    float prev[10], cur[10];
    prev[0] = 0.f;
#pragma unroll
    for (int m = 1; m <= 8; m++) {
        float v0 = cellf(raw, 0, m - 1), v1 = cellf(raw, m - 1, 0);
        prev[m] = prev[m - 1] + (dir ? v1 : v0);
    }
    prev[9] = prev[8];
#pragma unroll
    for (int l = 1; l < 8; l++) {
        float d[8];
#pragma unroll
        for (int j = 0; j < 8; j++) {
            float v0 = cellf(raw, l, j), v1 = cellf(raw, j, l);
            d[j] = dir ? v1 : v0;
        }
        cur[1] = d[0] + softmin3(prev[0], prev[1], 0.0f);
#pragma unroll
        for (int m = 2; m <= 8; m++)
            cur[m] = d[m - 1] + softmin2(prev[m - 1], cur[m - 1]);
        cur[9] = softmin3(prev[8], prev[9], cur[8]);   // pad column: d=0
#pragma unroll
        for (int m = 1; m < 10; m++) prev[m] = cur[m];
    }
    return prev[9];
}

#define EBS (32 * 72)   // shorts per wave epilogue buffer: 32 rows x 64 cols pad 72

// ---------------- Kernel 2: fused GEMM (full 128x128 + 128x32 tail) + DP + class mean ----
__global__ __launch_bounds__(256, 2) void gemm_kernel(
    const unsigned short* __restrict__ A,   // [MROWS][K] bf16 bits
    const unsigned short* __restrict__ B,   // [NPAD][K]  bf16 bits
    const float* __restrict__ nA, const float* __restrict__ nB,
    const int* __restrict__ labels,
    float* __restrict__ out)                // [QN][NCLS], zeroed by cvt
{
    __shared__ __align__(16) unsigned short smem[4 * EBS];   // 18432 B (staging aliases)
    unsigned short* Als = smem;             // 128*32 shorts
    unsigned short* Bls = smem + 4096;

    const int mt  = blockIdx.x;      // 0..127
    const int nt  = blockIdx.y;      // 0..6 (6 = tail)
    const int tid = threadIdx.x;
    const int lane = tid & 63;
    const int w    = tid >> 6;
    const int col  = lane & 15, kg = lane >> 4;
    const int mbase0 = mt * 128;

    const int c0 = tid, c1 = tid + 256;
    const unsigned short* Ab0 = A + (size_t)(mbase0 + (c0 >> 2)) * KK + (c0 & 3) * 8;
    const unsigned short* Ab1 = A + (size_t)(mbase0 + (c1 >> 2)) * KK + (c1 & 3) * 8;

    if (nt < 6) {
        // ---------------- full 128x128 path (R5 config) ----------------
        const int wm = (w & 1) * 64, wn = (w >> 1) * 64;
        f32x4 acc[4][4] = {};
        const unsigned short* Bb0 = B + (size_t)(nt * 128 + (c0 >> 2)) * KK + (c0 & 3) * 8;
        const unsigned short* Bb1 = B + (size_t)(nt * 128 + (c1 >> 2)) * KK + (c1 & 3) * 8;

        for (int kk = 0; kk < KK; kk += 32) {
            __syncthreads();
            gld16(Ab0 + kk, (char*)Als + c0 * 16);
            gld16(Ab1 + kk, (char*)Als + c1 * 16);
            gld16(Bb0 + kk, (char*)Bls + c0 * 16);
            gld16(Bb1 + kk, (char*)Bls + c1 * 16);
            __syncthreads();
            bf16x8 af[4], bfr[4];
#pragma unroll
            for (int i = 0; i < 4; i++) af[i]  = *(const bf16x8*)(Als + (wm + i * 16 + col) * 32 + kg * 8);
#pragma unroll
            for (int i = 0; i < 4; i++) bfr[i] = *(const bf16x8*)(Bls + (wn + i * 16 + col) * 32 + kg * 8);
#pragma unroll
            for (int mi = 0; mi < 4; mi++)
#pragma unroll
                for (int ni = 0; ni < 4; ni++)
                    acc[mi][ni] = __builtin_amdgcn_mfma_f32_16x16x32_bf16(af[mi], bfr[ni], acc[mi][ni], 0, 0, 0);
        }

        __syncthreads();   // staging reads done (epilogue aliases)
        unsigned short* eb = smem + w * EBS;
        const int mbase = mbase0 + wm;
        const int nbase = nt * 128 + wn;
        const int pr  = lane & 31;
        const int qv2 = pr >> 3, sv = pr & 7;
        const int dir = lane >> 5;

#pragma unroll
        for (int p = 0; p < 2; p++) {
            if (p) __syncthreads();
#pragma unroll
            for (int mi2 = 0; mi2 < 2; mi2++) {
                const int mi = p * 2 + mi2;
                float nx[4];
#pragma unroll
                for (int r = 0; r < 4; r++) nx[r] = nA[mbase + mi * 16 + kg * 4 + r];
#pragma unroll
                for (int ni = 0; ni < 4; ni++) {
                    const float ny = nB[nbase + ni * 16 + col];
#pragma unroll
                    for (int r = 0; r < 4; r++) {
                        float d = 1.0f - acc[mi][ni][r] * __builtin_amdgcn_rcpf(nx[r] * ny + 0.01f);
                        eb[(mi2 * 16 + kg * 4 + r) * 72 + ni * 16 + col] = f2bf(d);
                    }
                }
            }
            __syncthreads();

            uint4 raw[8];
            const unsigned short* tb = eb + (qv2 * 8) * 72 + sv * 8;
#pragma unroll
            for (int l = 0; l < 8; l++) raw[l] = *(const uint4*)(tb + l * 72);

            float res = otam_dp(raw, dir);
            res += __shfl_down(res, 32);
            if (dir == 0) {
                const int qg = mt * 16 + (wm >> 3) + p * 4 + qv2;
                const int sg = nt * 16 + (wn >> 3) + sv;
                atomicAdd(out + (size_t)qg * NCLS + labels[sg], -res * 0.2f);
            }
        }
    } else {
        // ---------------- 128x32 tail path (N cols 768..799) ----------------
        const int wm = w * 32;           // 4 waves cover 128 M-rows, all share 32 N-cols
        f32x4 acc[2][2] = {};
        const unsigned short* Bb0 = B + (size_t)(768 + (tid >> 2)) * KK + (tid & 3) * 8;  // tid<128

        for (int kk = 0; kk < KK; kk += 32) {
            __syncthreads();
            gld16(Ab0 + kk, (char*)Als + c0 * 16);
            gld16(Ab1 + kk, (char*)Als + c1 * 16);
            if (tid < 128) gld16(Bb0 + kk, (char*)Bls + tid * 16);
            __syncthreads();
            bf16x8 af[2], bfr[2];
#pragma unroll
            for (int i = 0; i < 2; i++) af[i]  = *(const bf16x8*)(Als + (wm + i * 16 + col) * 32 + kg * 8);
#pragma unroll
            for (int i = 0; i < 2; i++) bfr[i] = *(const bf16x8*)(Bls + (i * 16 + col) * 32 + kg * 8);
#pragma unroll
            for (int mi = 0; mi < 2; mi++)
#pragma unroll
                for (int ni = 0; ni < 2; ni++)
                    acc[mi][ni] = __builtin_amdgcn_mfma_f32_16x16x32_bf16(af[mi], bfr[ni], acc[mi][ni], 0, 0, 0);
        }

        __syncthreads();   // staging reads done
        unsigned short* eb = smem + w * EBS;   // 32 rows x 32 cols, stride 40 (1280 shorts used)
        const int mbase = mbase0 + wm;

#pragma unroll
        for (int mi = 0; mi < 2; mi++) {
            float nx[4];
#pragma unroll
            for (int r = 0; r < 4; r++) nx[r] = nA[mbase + mi * 16 + kg * 4 + r];
#pragma unroll
            for (int ni = 0; ni < 2; ni++) {
                const float ny = nB[768 + ni * 16 + col];
#pragma unroll
                for (int r = 0; r < 4; r++) {
                    float d = 1.0f - acc[mi][ni][r] * __builtin_amdgcn_rcpf(nx[r] * ny + 0.01f);
                    eb[(mi * 16 + kg * 4 + r) * 40 + ni * 16 + col] = f2bf(d);
                }
            }
        }
        __syncthreads();

        // DP: 4 qv x 4 sv = 16 pairs x 2 dirs = 32 active lanes
        const int pr  = lane & 31;
        const int qv2 = (pr & 15) >> 2, sv = pr & 3;
        const int dir = lane >> 5;
        uint4 raw[8];
        const unsigned short* tb = eb + (qv2 * 8) * 40 + sv * 8;
#pragma unroll
        for (int l = 0; l < 8; l++) raw[l] = *(const uint4*)(tb + l * 40);

        float res = otam_dp(raw, dir);
        res += __shfl_down(res, 32);
        if (dir == 0 && pr < 16) {
            const int qg = mt * 16 + w * 4 + qv2;
            const int sg = 96 + sv;
            atomicAdd(out + (size_t)qg * NCLS + labels[sg], -res * 0.2f);
        }
    }
}

// ---------------- launch ----------------
extern "C" void kernel_launch(void* const* d_in, const int* in_sizes, int n_in,
                              void* d_out, int out_size, void* d_ws, size_t ws_size,
                              hipStream_t stream)
{
    const float* tf     = (const float*)d_in[0];   // [2048,8,2048] f32
    const float* sf     = (const float*)d_in[1];   // [100,8,2048]  f32
    const int*   labels = (const int*)d_in[2];     // [100] i32
    float* out = (float*)d_out;                    // [1,2048,20] f32

    char* ws = (char*)d_ws;
    const size_t szA    = (size_t)MROWS * KK * 2;      // 67108864
    const size_t szB    = (size_t)NPAD  * KK * 2;      // 3276800
    const size_t szNA   = (size_t)MROWS * 4;           // 65536
    unsigned short* Abf = (unsigned short*)ws;
    unsigned short* Bbf = (unsigned short*)(ws + szA);
    float* nA   = (float*)(ws + szA + szB);
    float* nB   = (float*)(ws + szA + szB + szNA);

    cvt_kernel<<<(MROWS + NPAD) / 4, 256, 0, stream>>>(tf, sf, Abf, Bbf, nA, nB, out);
    gemm_kernel<<<dim3(MROWS / 128, 7), 256, 0, stream>>>(Abf, Bbf, nA, nB, labels, out);
}